// Round 6
// baseline (929.474 us; speedup 1.0000x reference)
//
#include <hip/hip_runtime.h>

// ============================================================================
// MixerBlock (attention QK^T/softmax is dead code; heads = V only):
//   x1 = LN1(patches); sa = x1 @ Wc^T + bc  (Wc = out_w @ Wv, precomputed)
//   x2 = sa + x1 (bf16, ws); x3 = LN2(x2)
//   h = selu(x3 @ w1^T + b1); out = h @ w2^T + b2 + x3
// R12: residency lever, round 3. Ladder so far (MLP1 dur / MfmaUtil / Occ):
//   R6 8w 96KB: 110/30/22   R7-R9 8-phase 128KB: 124-127/25/22
//   R10 8w 72KB: 112/28/22  R11 4w 48KB: 110/30/30
//   -> co-residency threshold found: LDS <= 64 KiB/block needed (72 KiB
//      still 1 block/CU); 48 KiB gave 2.4 blocks but MfmaUtil flat ->
//      2.4 waves/SIMD still too few to fill the per-wave serial chain.
//   R12: ring 3 -> 2 stages (32 KiB/block) -> 5 blocks/CU, 20 waves/CU
//   (62%), __launch_bounds__(256,5). Distance-1 prefetch + VM0 drain per
//   K-step = m97's exact verified regime (874-912 TF, MfmaUtil 37% at
//   ~3 blocks/CU; m114: block TLP absorbs the drain stall).
//   Buffer-free proof: step-s barrier follows all step-(s-1) reads
//   (lgkm-enforced before MFMA); issue-into-freed-buffer follows barrier.
//   Works for any even T (24, 96 ok).
// Kept: 128x128 tile, 4 waves 2x2 (wave 64x64, acc[4][4]), 16x16x32 MFMA,
// chunk swizzle (0 bank conflicts), global_load_lds w16, XCD m-band remap,
// bf16 X2 residency, merged casts, EPI fusion.
// ============================================================================

typedef __bf16 bf16;
typedef __bf16 bf16x8 __attribute__((ext_vector_type(8)));
typedef __bf16 bf16x4 __attribute__((ext_vector_type(4)));
typedef float  f32x4  __attribute__((ext_vector_type(4)));

#define N_ROWS  16384   // B*S = 8*2048

#define AS1(p) ((const __attribute__((address_space(1))) void*)(p))
#define AS3(p) ((__attribute__((address_space(3))) void*)(p))

// s_waitcnt imm (gfx9): vmcnt[3:0]|[15:14], expcnt[6:4]=7, lgkmcnt[11:8]=0xF
#define VM0 0x0F70

// ---------------------------------------------------------------------------
// merged fp32->bf16 casts: mlp_w1 | mlp_w2 | out_w (4 elems/thread)
#define N1 589824   // 3072*768/4
#define N2 589824   // 768*3072/4
#define N3 147456   // 768*768/4
__global__ __launch_bounds__(256) void prep_cast(const float* __restrict__ w1,
                                                 const float* __restrict__ w2,
                                                 const float* __restrict__ ow,
                                                 bf16* __restrict__ w1b,
                                                 bf16* __restrict__ w2b,
                                                 bf16* __restrict__ owb) {
  int i = blockIdx.x * 256 + threadIdx.x;
  const float* src; bf16* dst; int off;
  if (i < N1)           { src = w1; dst = w1b; off = i; }
  else if (i < N1 + N2) { src = w2; dst = w2b; off = i - N1; }
  else                  { src = ow; dst = owb; off = i - N1 - N2; }
  float4 v = ((const float4*)src)[off];
  bf16x4 o = {(bf16)v.x, (bf16)v.y, (bf16)v.z, (bf16)v.w};
  *(bf16x4*)(dst + 4 * (size_t)off) = o;
}

// ---------------------------------------------------------------------------
// WvT[k][j] = in_weight[(j*3+2)*768 + k], LDS-tiled 64x64 (coalesced both ways)
__global__ __launch_bounds__(256) void wvt_kernel(const float* __restrict__ in_weight,
                                                  bf16* __restrict__ wvt) {
  __shared__ float t[64][65];
  const int k0 = blockIdx.x * 64, j0 = blockIdx.y * 64;
  const int tx = threadIdx.x & 63, ty = threadIdx.x >> 6;
  for (int jj = ty; jj < 64; jj += 4)
    t[jj][tx] = in_weight[((size_t)(j0 + jj) * 3 + 2) * 768 + k0 + tx];
  __syncthreads();
  for (int kk = ty; kk < 64; kk += 4)
    wvt[(size_t)(k0 + kk) * 768 + j0 + tx] = (bf16)t[tx][kk];
}

// ---------------------------------------------------------------------------
__global__ __launch_bounds__(64) void bias_combine_kernel(const float* __restrict__ out_w,
                                                          const float* __restrict__ in_bias,
                                                          const float* __restrict__ out_b,
                                                          float* __restrict__ bc) {
  int n = blockIdx.x, l = threadIdx.x;
  float s = 0.f;
  for (int j = l; j < 768; j += 64) s += out_w[(size_t)n * 768 + j] * in_bias[j * 3 + 2];
#pragma unroll
  for (int off = 32; off > 0; off >>= 1) s += __shfl_xor(s, off, 64);
  if (l == 0) bc[n] = s + out_b[n];
}

// ---------------------------------------------------------------------------
// LayerNorm: one row (768) per 256-thread block. TIN = float or bf16.
template <typename TIN>
__global__ __launch_bounds__(256) void ln_kernel(const TIN* __restrict__ x,
                                                 const float* __restrict__ g,
                                                 const float* __restrict__ b,
                                                 bf16* __restrict__ y) {
  const int row = blockIdx.x;
  const TIN* xr = x + (size_t)row * 768;
  float v[3], s1 = 0.f, s2 = 0.f;
#pragma unroll
  for (int i = 0; i < 3; ++i) {
    v[i] = (float)xr[threadIdx.x + i * 256];
    s1 += v[i];
    s2 += v[i] * v[i];
  }
#pragma unroll
  for (int off = 32; off > 0; off >>= 1) {
    s1 += __shfl_xor(s1, off, 64);
    s2 += __shfl_xor(s2, off, 64);
  }
  __shared__ float red[8];
  int w = threadIdx.x >> 6, l = threadIdx.x & 63;
  if (l == 0) { red[w * 2] = s1; red[w * 2 + 1] = s2; }
  __syncthreads();
  s1 = red[0] + red[2] + red[4] + red[6];
  s2 = red[1] + red[3] + red[5] + red[7];
  const float mu = s1 * (1.f / 768.f);
  const float var = s2 * (1.f / 768.f) - mu * mu;
  const float rstd = rsqrtf(var + 1e-5f);
#pragma unroll
  for (int i = 0; i < 3; ++i) {
    int d = threadIdx.x + i * 256;
    y[(size_t)row * 768 + d] = (bf16)((v[i] - mu) * rstd * g[d] + b[d]);
  }
}

// ---------------------------------------------------------------------------
// C[M][N] = A[M][K] @ B[N][K]^T (+ epilogue). Block tile 128x128, BK=32,
// 256 threads = 4 waves in 2x2 (wave tile 64x64, acc[4][4]). 2-stage LDS
// double-buffer (32 KB -> 5 blocks/CU, 20 waves/CU), distance-1 prefetch,
// VM0 drain per K-step (m97 regime; block TLP absorbs the drain stall).
// Requires K % 64 == 0 (T even); M,N % 128 == 0.
// EPI 0: bf16=acc | EPI 1: f32=acc+bias+resid | EPI 2: bf16=selu(acc+bias)
// EPI 3: bf16=acc+bias+resid
#define SLOT_E (256 * 32)   // (128 A-rows + 128 B-rows) * 32 k
template <int EPI>
__global__ __launch_bounds__(256, 5) void gemm_bt(const bf16* __restrict__ A,
                                                  const bf16* __restrict__ B,
                                                  const float* __restrict__ bias,
                                                  const bf16* __restrict__ resid,
                                                  void* __restrict__ out,
                                                  int M, int N, int K) {
  __shared__ bf16 ring[2 * SLOT_E];   // 32 KB
  const int tid = threadIdx.x;
  const int w = tid >> 6, l = tid & 63;
  const int wr = w >> 1, wcn = w & 1;       // 2x2 wave grid
  const int q = l >> 4, m16 = l & 15;

  // XCD-aware remap (XCD = linear%8): each XCD owns a contiguous band of
  // gridy/8 m-strips, m fastest -> B panel L2-resident across the band.
  int mtile, ntile;
  {
    const int L = blockIdx.y * gridDim.x + blockIdx.x;
    const int gy = gridDim.y;
    if ((gy & 7) == 0) {
      const int mpx = gy >> 3;
      const int xcd = L & 7;
      const int slot = L >> 3;
      mtile = xcd * mpx + (slot % mpx);
      ntile = slot / mpx;
    } else {
      mtile = blockIdx.y; ntile = blockIdx.x;
    }
  }
  const long tileM = (long)mtile * 128;
  const long tileN = (long)ntile * 128;

  // staging geometry (chunk swizzle: stored col (ch&3) holds logical col
  // ((ch&3)-(row>>1))&3 -> frag ds_read_b128 conflict-free).
  // A: 512 chunks = 2/thread; B: 512 chunks = 2/thread.
  const bf16* gA[2]; int ldA[2];
  const bf16* gB[2]; int ldB[2];
#pragma unroll
  for (int j = 0; j < 2; ++j) {
    const int ch = tid + j * 256;
    const int row = ch >> 2;
    const int cl = ((ch & 3) - (row >> 1)) & 3;
    gA[j] = A + (tileM + row) * (long)K + cl * 8;
    gB[j] = B + (tileN + row) * (long)K + cl * 8;
    ldA[j] = ch * 8;
    ldB[j] = ch * 8;
  }

  // fragment LDS offsets (logical (r,q) lives at r*32 + ((q+(r>>1))&3)*8)
  int offA[4], offB[4];
#pragma unroll
  for (int mi = 0; mi < 4; ++mi) {
    const int r = wr * 64 + mi * 16 + m16;
    offA[mi] = r * 32 + (((q + (r >> 1)) & 3) << 3);
  }
#pragma unroll
  for (int ni = 0; ni < 4; ++ni) {
    const int r = wcn * 64 + ni * 16 + m16;
    offB[ni] = r * 32 + (((q + (r >> 1)) & 3) << 3);
  }

  f32x4 acc[4][4] = {};

  // prologue: stage 0 -> buf0 (4 loads/thread: 2 A + 2 B)
  {
    bf16* da = ring;
    bf16* db = ring + 128 * 32;
#pragma unroll
    for (int j = 0; j < 2; ++j) {
      __builtin_amdgcn_global_load_lds(AS1(gA[j]), AS3(&da[ldA[j]]), 16, 0, 0);
      __builtin_amdgcn_global_load_lds(AS1(gB[j]), AS3(&db[ldB[j]]), 16, 0, 0);
    }
  }
  long k_next = 32;

  // one K-step: VM0 (own stage-SLOT loads landed) -> barrier (everyone's
  // landed + buf SLOT^1 fully read by all) -> issue stage into SLOT^1 ->
  // compute stage SLOT (16 MFMA, 8 ds_read_b128).
#define KSTEP(SLOT, ISSUE)                                                     \
  {                                                                            \
    __builtin_amdgcn_s_waitcnt(VM0);                                           \
    __builtin_amdgcn_s_barrier();                                              \
    if (ISSUE) {                                                               \
      bf16* da = ring + ((SLOT) ^ 1) * SLOT_E;                                 \
      bf16* db = da + 128 * 32;                                                \
      _Pragma("unroll")                                                        \
      for (int j = 0; j < 2; ++j) {                                            \
        __builtin_amdgcn_global_load_lds(AS1(gA[j] + k_next), AS3(&da[ldA[j]]), 16, 0, 0); \
        __builtin_amdgcn_global_load_lds(AS1(gB[j] + k_next), AS3(&db[ldB[j]]), 16, 0, 0); \
      }                                                                        \
      k_next += 32;                                                            \
    }                                                                          \
    const bf16* ca = ring + (SLOT) * SLOT_E;                                   \
    const bf16* cb = ca + 128 * 32;                                            \
    bf16x8 bfr[4];                                                             \
    _Pragma("unroll")                                                          \
    for (int ni = 0; ni < 4; ++ni) bfr[ni] = *(const bf16x8*)&cb[offB[ni]];    \
    _Pragma("unroll")                                                          \
    for (int mi = 0; mi < 4; ++mi) {                                           \
      const bf16x8 af = *(const bf16x8*)&ca[offA[mi]];                         \
      _Pragma("unroll")                                                        \
      for (int ni = 0; ni < 4; ++ni)                                           \
        acc[mi][ni] = __builtin_amdgcn_mfma_f32_16x16x32_bf16(af, bfr[ni],     \
                                                              acc[mi][ni], 0, 0, 0); \
    }                                                                          \
  }

  const int T = K >> 5;   // caller guarantees T even, T >= 2
#pragma unroll 1
  for (int g = 0; g < T - 2; g += 2) {
    KSTEP(0, 1) KSTEP(1, 1)
  }
  KSTEP(0, 1) KSTEP(1, 0)
#undef KSTEP

  // epilogue: C/D layout col = lane&15, row = (lane>>4)*4 + reg (m89-verified)
  const long colBase = tileN + (long)wcn * 64 + m16;
  const long rowBase = tileM + (long)wr * 64 + q * 4;
#pragma unroll
  for (int mi = 0; mi < 4; ++mi) {
#pragma unroll
    for (int r = 0; r < 4; ++r) {
      const long row = rowBase + mi * 16 + r;
#pragma unroll
      for (int ni = 0; ni < 4; ++ni) {
        const long col = colBase + ni * 16;
        float v = acc[mi][ni][r];
        if (EPI == 0) {
          ((bf16*)out)[row * N + col] = (bf16)v;
        } else if (EPI == 1) {
          v += bias[col] + (float)resid[row * N + col];
          ((float*)out)[row * N + col] = v;
        } else if (EPI == 2) {
          v += bias[col];
          v = v > 0.f ? 1.0507009873554805f * v
                      : 1.0507009873554805f * 1.6732632423543772f * (__expf(v) - 1.f);
          ((bf16*)out)[row * N + col] = (bf16)v;
        } else {  // EPI == 3: bf16 = acc + bias + resid
          v += bias[col] + (float)resid[row * N + col];
          ((bf16*)out)[row * N + col] = (bf16)v;
        }
      }
    }
  }
}

// ---------------------------------------------------------------------------
extern "C" void kernel_launch(void* const* d_in, const int* in_sizes, int n_in,
                              void* d_out, int out_size, void* d_ws, size_t ws_size,
                              hipStream_t stream) {
  const float* patches   = (const float*)d_in[0];
  const float* in_weight = (const float*)d_in[1];
  const float* in_bias   = (const float*)d_in[2];
  const float* out_w     = (const float*)d_in[3];
  const float* out_b     = (const float*)d_in[4];
  const float* mlp_w1    = (const float*)d_in[5];
  const float* mlp_b1    = (const float*)d_in[6];
  const float* mlp_w2    = (const float*)d_in[7];
  const float* mlp_b2    = (const float*)d_in[8];
  const float* ln1_g     = (const float*)d_in[9];
  const float* ln1_b     = (const float*)d_in[10];
  const float* ln2_g     = (const float*)d_in[11];
  const float* ln2_b     = (const float*)d_in[12];

  char* ws = (char*)d_ws;
  const size_t MB = 1024 * 1024;
  bf16* Wc   = (bf16*)(ws + 0);        // [768][768] combined proj weight
  bf16* w1b  = (bf16*)(ws + 2 * MB);
  bf16* w2b  = (bf16*)(ws + 8 * MB);
  bf16* owb  = (bf16*)(ws + 14 * MB);
  bf16* wvt  = (bf16*)(ws + 16 * MB);
  float* bc  = (float*)(ws + 18 * MB);
  bf16* X1   = (bf16*)(ws + 20 * MB);  // 25 MB; reused as X3 after proj
  bf16* X3   = (bf16*)(ws + 20 * MB);
  bf16* X2b  = (bf16*)(ws + 48 * MB);  // 25 MB; dead before H written
  bf16* H    = (bf16*)(ws + 48 * MB);  // 100 MB (aliases X2b - safe, see order)

  prep_cast<<<(N1 + N2 + N3) / 256, 256, 0, stream>>>(mlp_w1, mlp_w2, out_w,
                                                      w1b, w2b, owb);
  wvt_kernel<<<dim3(12, 12), 256, 0, stream>>>(in_weight, wvt);
  bias_combine_kernel<<<768, 64, 0, stream>>>(out_w, in_bias, out_b, bc);
  // Wc[n][k] = sum_j out_w[n][j] * WvT[k][j]
  gemm_bt<0><<<dim3(6, 6), 256, 0, stream>>>(owb, wvt, nullptr, nullptr, Wc, 768, 768, 768);

  ln_kernel<float><<<N_ROWS, 256, 0, stream>>>(patches, ln1_g, ln1_b, X1);
  // x2 = x1 @ Wc^T + bc + x1  (bf16)
  gemm_bt<3><<<dim3(6, 128), 256, 0, stream>>>(X1, Wc, bc, X1, X2b, N_ROWS, 768, 768);
  ln_kernel<bf16><<<N_ROWS, 256, 0, stream>>>(X2b, ln2_g, ln2_b, X3);
  // h = selu(x3 @ w1^T + b1)   (overwrites X2b region - X2b is dead)
  gemm_bt<2><<<dim3(24, 128), 256, 0, stream>>>(X3, w1b, mlp_b1, nullptr, H, N_ROWS, 3072, 768);
  // out = h @ w2^T + b2 + x3   (fp32 final)
  gemm_bt<1><<<dim3(6, 128), 256, 0, stream>>>(H, w2b, mlp_b2, X3, d_out, N_ROWS, 768, 3072);
}

// Round 7
// 412.660 us; speedup vs baseline: 2.2524x; 2.2524x over previous
//
#include <hip/hip_runtime.h>

// ============================================================================
// MixerBlock (attention QK^T/softmax is dead code; heads = V only):
//   x1 = LN1(patches); sa = x1 @ Wc^T + bc  (Wc = out_w @ Wv, precomputed)
//   x2 = sa + x1 (bf16, ws); x3 = LN2(x2)
//   h = selu(x3 @ w1^T + b1); out = h @ w2^T + b2 + x3
// R13 = recovery + recombination of proven components:
//   - R12 post-mortem: __launch_bounds__(256,5) capped unified VGPR+AGPR at
//     ~102/wave; acc spilled to scratch (VGPR_Count 48, WRITE_SIZE 634 MB,
//     MfmaUtil 9%). With 64x64 wave tiles + acc[4][4], 3 blocks/CU is the
//     VGPR ceiling -> R11's (256,3) + 48 KiB LDS is the residency optimum.
//   - Totals analysis: MLPs ~220 us in all good rounds; "rest" was 143 us
//     with 256^2 8-phase gemm (R9) vs 171-180 us with 128^2 (R6/R11) ->
//     proj (16384x768x768, N=768) is ~25-30 us faster at 256^2 tiles
//     (192 big blocks vs 768 small, less B re-read); MLPs are faster at
//     128^2 (110 vs 124). Use BOTH: gemm128 for MLPs, gemm256 for proj+Wc.
//   Both kernels verbatim from previously-passing rounds (R11 / R9).
// Kept: 16x16x32 MFMA, chunk swizzle (0 bank conflicts), global_load_lds
// w16, XCD m-band remap, bf16 X2 residency, merged casts, EPI fusion.
// ============================================================================

typedef __bf16 bf16;
typedef __bf16 bf16x8 __attribute__((ext_vector_type(8)));
typedef __bf16 bf16x4 __attribute__((ext_vector_type(4)));
typedef float  f32x4  __attribute__((ext_vector_type(4)));

#define N_ROWS  16384   // B*S = 8*2048

#define AS1(p) ((const __attribute__((address_space(1))) void*)(p))
#define AS3(p) ((__attribute__((address_space(3))) void*)(p))

// s_waitcnt imm (gfx9): vmcnt[3:0]|[15:14], expcnt[6:4]=7, lgkmcnt[11:8]=0xF
#define VM4 0x0F74
#define VM0 0x0F70
#define WAIT8  __builtin_amdgcn_s_waitcnt(0x0F78)
#define WAIT6  __builtin_amdgcn_s_waitcnt(0x0F76)
#define WAIT2  __builtin_amdgcn_s_waitcnt(0x0F72)
#define WAIT0  __builtin_amdgcn_s_waitcnt(0x0F70)
#define NOWAIT (void)0

// ---------------------------------------------------------------------------
// merged fp32->bf16 casts: mlp_w1 | mlp_w2 | out_w (4 elems/thread)
#define N1 589824   // 3072*768/4
#define N2 589824   // 768*3072/4
#define N3 147456   // 768*768/4
__global__ __launch_bounds__(256) void prep_cast(const float* __restrict__ w1,
                                                 const float* __restrict__ w2,
                                                 const float* __restrict__ ow,
                                                 bf16* __restrict__ w1b,
                                                 bf16* __restrict__ w2b,
                                                 bf16* __restrict__ owb) {
  int i = blockIdx.x * 256 + threadIdx.x;
  const float* src; bf16* dst; int off;
  if (i < N1)           { src = w1; dst = w1b; off = i; }
  else if (i < N1 + N2) { src = w2; dst = w2b; off = i - N1; }
  else                  { src = ow; dst = owb; off = i - N1 - N2; }
  float4 v = ((const float4*)src)[off];
  bf16x4 o = {(bf16)v.x, (bf16)v.y, (bf16)v.z, (bf16)v.w};
  *(bf16x4*)(dst + 4 * (size_t)off) = o;
}

// ---------------------------------------------------------------------------
// WvT[k][j] = in_weight[(j*3+2)*768 + k], LDS-tiled 64x64 (coalesced both ways)
__global__ __launch_bounds__(256) void wvt_kernel(const float* __restrict__ in_weight,
                                                  bf16* __restrict__ wvt) {
  __shared__ float t[64][65];
  const int k0 = blockIdx.x * 64, j0 = blockIdx.y * 64;
  const int tx = threadIdx.x & 63, ty = threadIdx.x >> 6;
  for (int jj = ty; jj < 64; jj += 4)
    t[jj][tx] = in_weight[((size_t)(j0 + jj) * 3 + 2) * 768 + k0 + tx];
  __syncthreads();
  for (int kk = ty; kk < 64; kk += 4)
    wvt[(size_t)(k0 + kk) * 768 + j0 + tx] = (bf16)t[tx][kk];
}

// ---------------------------------------------------------------------------
__global__ __launch_bounds__(64) void bias_combine_kernel(const float* __restrict__ out_w,
                                                          const float* __restrict__ in_bias,
                                                          const float* __restrict__ out_b,
                                                          float* __restrict__ bc) {
  int n = blockIdx.x, l = threadIdx.x;
  float s = 0.f;
  for (int j = l; j < 768; j += 64) s += out_w[(size_t)n * 768 + j] * in_bias[j * 3 + 2];
#pragma unroll
  for (int off = 32; off > 0; off >>= 1) s += __shfl_xor(s, off, 64);
  if (l == 0) bc[n] = s + out_b[n];
}

// ---------------------------------------------------------------------------
// LayerNorm: one row (768) per 256-thread block. TIN = float or bf16.
template <typename TIN>
__global__ __launch_bounds__(256) void ln_kernel(const TIN* __restrict__ x,
                                                 const float* __restrict__ g,
                                                 const float* __restrict__ b,
                                                 bf16* __restrict__ y) {
  const int row = blockIdx.x;
  const TIN* xr = x + (size_t)row * 768;
  float v[3], s1 = 0.f, s2 = 0.f;
#pragma unroll
  for (int i = 0; i < 3; ++i) {
    v[i] = (float)xr[threadIdx.x + i * 256];
    s1 += v[i];
    s2 += v[i] * v[i];
  }
#pragma unroll
  for (int off = 32; off > 0; off >>= 1) {
    s1 += __shfl_xor(s1, off, 64);
    s2 += __shfl_xor(s2, off, 64);
  }
  __shared__ float red[8];
  int w = threadIdx.x >> 6, l = threadIdx.x & 63;
  if (l == 0) { red[w * 2] = s1; red[w * 2 + 1] = s2; }
  __syncthreads();
  s1 = red[0] + red[2] + red[4] + red[6];
  s2 = red[1] + red[3] + red[5] + red[7];
  const float mu = s1 * (1.f / 768.f);
  const float var = s2 * (1.f / 768.f) - mu * mu;
  const float rstd = rsqrtf(var + 1e-5f);
#pragma unroll
  for (int i = 0; i < 3; ++i) {
    int d = threadIdx.x + i * 256;
    y[(size_t)row * 768 + d] = (bf16)((v[i] - mu) * rstd * g[d] + b[d]);
  }
}

// ---------------------------------------------------------------------------
// gemm128: C[M][N] = A[M][K] @ B[N][K]^T (+ epilogue). Block tile 128x128,
// BK=32, 256 threads = 4 waves 2x2 (wave tile 64x64, acc[4][4]). 3-stage LDS
// ring (48 KB -> up to 3 blocks/CU), prefetch distance 2, counted vmcnt.
// Requires K/32 % 3 == 0 (24, 96 ok); M,N % 128 == 0.  [R11 verbatim]
// EPI 0: bf16=acc | EPI 1: f32=acc+bias+resid | EPI 2: bf16=selu(acc+bias)
// EPI 3: bf16=acc+bias+resid
#define SLOT_E (256 * 32)   // (128 A-rows + 128 B-rows) * 32 k
template <int EPI>
__global__ __launch_bounds__(256, 3) void gemm128(const bf16* __restrict__ A,
                                                  const bf16* __restrict__ B,
                                                  const float* __restrict__ bias,
                                                  const bf16* __restrict__ resid,
                                                  void* __restrict__ out,
                                                  int M, int N, int K) {
  __shared__ bf16 ring[3 * SLOT_E];   // 48 KB
  const int tid = threadIdx.x;
  const int w = tid >> 6, l = tid & 63;
  const int wr = w >> 1, wcn = w & 1;       // 2x2 wave grid
  const int q = l >> 4, m16 = l & 15;

  // XCD-aware remap (XCD = linear%8): each XCD owns a contiguous band of
  // gridy/8 m-strips, m fastest -> A band L2-resident across n-tiles.
  int mtile, ntile;
  {
    const int L = blockIdx.y * gridDim.x + blockIdx.x;
    const int gy = gridDim.y;
    if ((gy & 7) == 0) {
      const int mpx = gy >> 3;
      const int xcd = L & 7;
      const int slot = L >> 3;
      mtile = xcd * mpx + (slot % mpx);
      ntile = slot / mpx;
    } else {
      mtile = blockIdx.y; ntile = blockIdx.x;
    }
  }
  const long tileM = (long)mtile * 128;
  const long tileN = (long)ntile * 128;

  // staging geometry (chunk swizzle: stored col (ch&3) holds logical col
  // ((ch&3)-(row>>1))&3 -> frag ds_read_b128 conflict-free).
  const bf16* gA[2]; int ldA[2];
  const bf16* gB[2]; int ldB[2];
#pragma unroll
  for (int j = 0; j < 2; ++j) {
    const int ch = tid + j * 256;
    const int row = ch >> 2;
    const int cl = ((ch & 3) - (row >> 1)) & 3;
    gA[j] = A + (tileM + row) * (long)K + cl * 8;
    gB[j] = B + (tileN + row) * (long)K + cl * 8;
    ldA[j] = ch * 8;
    ldB[j] = ch * 8;
  }

  // fragment LDS offsets (logical (r,q) lives at r*32 + ((q+(r>>1))&3)*8)
  int offA[4], offB[4];
#pragma unroll
  for (int mi = 0; mi < 4; ++mi) {
    const int r = wr * 64 + mi * 16 + m16;
    offA[mi] = r * 32 + (((q + (r >> 1)) & 3) << 3);
  }
#pragma unroll
  for (int ni = 0; ni < 4; ++ni) {
    const int r = wcn * 64 + ni * 16 + m16;
    offB[ni] = r * 32 + (((q + (r >> 1)) & 3) << 3);
  }

  f32x4 acc[4][4] = {};

  // prologue: stages 0..1 (4 loads/thread each: 2 A + 2 B)
#pragma unroll
  for (int s = 0; s < 2; ++s) {
    bf16* da = ring + s * SLOT_E;
    bf16* db = da + 128 * 32;
#pragma unroll
    for (int j = 0; j < 2; ++j) {
      __builtin_amdgcn_global_load_lds(AS1(gA[j] + s * 32), AS3(&da[ldA[j]]), 16, 0, 0);
      __builtin_amdgcn_global_load_lds(AS1(gB[j] + s * 32), AS3(&db[ldB[j]]), 16, 0, 0);
    }
  }
  long k_next = 64;

  // one K-step: wait(stage SLOT landed) -> barrier -> issue stage SLOT+2 ->
  // compute stage SLOT (16 MFMA, 8 ds_read_b128)
#define KSTEP(SLOT, WIMM, ISSUE)                                               \
  {                                                                            \
    __builtin_amdgcn_s_waitcnt(WIMM);                                          \
    __builtin_amdgcn_s_barrier();                                              \
    if (ISSUE) {                                                               \
      bf16* da = ring + (((SLOT) + 2) % 3) * SLOT_E;                           \
      bf16* db = da + 128 * 32;                                                \
      _Pragma("unroll")                                                        \
      for (int j = 0; j < 2; ++j) {                                            \
        __builtin_amdgcn_global_load_lds(AS1(gA[j] + k_next), AS3(&da[ldA[j]]), 16, 0, 0); \
        __builtin_amdgcn_global_load_lds(AS1(gB[j] + k_next), AS3(&db[ldB[j]]), 16, 0, 0); \
      }                                                                        \
      k_next += 32;                                                            \
    }                                                                          \
    const bf16* ca = ring + (SLOT) * SLOT_E;                                   \
    const bf16* cb = ca + 128 * 32;                                            \
    bf16x8 bfr[4];                                                             \
    _Pragma("unroll")                                                          \
    for (int ni = 0; ni < 4; ++ni) bfr[ni] = *(const bf16x8*)&cb[offB[ni]];    \
    _Pragma("unroll")                                                          \
    for (int mi = 0; mi < 4; ++mi) {                                           \
      const bf16x8 af = *(const bf16x8*)&ca[offA[mi]];                         \
      _Pragma("unroll")                                                        \
      for (int ni = 0; ni < 4; ++ni)                                           \
        acc[mi][ni] = __builtin_amdgcn_mfma_f32_16x16x32_bf16(af, bfr[ni],     \
                                                              acc[mi][ni], 0, 0, 0); \
    }                                                                          \
  }

  const int T = K >> 5;   // caller guarantees T % 3 == 0, T >= 6
#pragma unroll 1
  for (int g = 0; g < T - 3; g += 3) {
    KSTEP(0, VM4, 1) KSTEP(1, VM4, 1) KSTEP(2, VM4, 1)
  }
  KSTEP(0, VM4, 1) KSTEP(1, VM4, 0) KSTEP(2, VM0, 0)
#undef KSTEP

  // epilogue: C/D layout col = lane&15, row = (lane>>4)*4 + reg (m89-verified)
  const long colBase = tileN + (long)wcn * 64 + m16;
  const long rowBase = tileM + (long)wr * 64 + q * 4;
#pragma unroll
  for (int mi = 0; mi < 4; ++mi) {
#pragma unroll
    for (int r = 0; r < 4; ++r) {
      const long row = rowBase + mi * 16 + r;
#pragma unroll
      for (int ni = 0; ni < 4; ++ni) {
        const long col = colBase + ni * 16;
        float v = acc[mi][ni][r];
        if (EPI == 0) {
          ((bf16*)out)[row * N + col] = (bf16)v;
        } else if (EPI == 1) {
          v += bias[col] + (float)resid[row * N + col];
          ((float*)out)[row * N + col] = v;
        } else if (EPI == 2) {
          v += bias[col];
          v = v > 0.f ? 1.0507009873554805f * v
                      : 1.0507009873554805f * 1.6732632423543772f * (__expf(v) - 1.f);
          ((bf16*)out)[row * N + col] = (bf16)v;
        } else {  // EPI == 3: bf16 = acc + bias + resid
          v += bias[col] + (float)resid[row * N + col];
          ((bf16*)out)[row * N + col] = (bf16)v;
        }
      }
    }
  }
}

// ---------------------------------------------------------------------------
// gemm256: block tile 256x256, BK=64, 512 threads = 8 waves (2x4), wave tile
// 128x64, acc[8][4]. 8-phase schedule over 2 K-tiles (128 KiB LDS, 1 blk/CU).
// [R9 verbatim - best for small-N GEMMs (proj N=768, Wc) where fewer, bigger
// blocks cut B re-reads; worse than gemm128 for the MLPs.]
// Requires K % 128 == 0, K >= 256; M,N % 256 == 0.
template <int EPI>
__global__ __launch_bounds__(512, 2) void gemm256(const bf16* __restrict__ A,
                                                  const bf16* __restrict__ B,
                                                  const float* __restrict__ bias,
                                                  const bf16* __restrict__ resid,
                                                  void* __restrict__ out,
                                                  int M, int N, int K) {
  __shared__ bf16 ring[65536];   // 128 KiB = 2 bufs x (A 16384 + B 16384 elems)
  const int tid = threadIdx.x;
  const int w = tid >> 6, l = tid & 63;
  const int wr = w >> 2, wcn = w & 3;       // 2x4 wave grid
  const int q = l >> 4, m16 = l & 15;

  int mtile, ntile;
  {
    const int L = blockIdx.y * gridDim.x + blockIdx.x;
    const int gy = gridDim.y;
    if ((gy & 7) == 0) {
      const int mpx = gy >> 3;
      const int xcd = L & 7;
      const int slot = L >> 3;
      mtile = xcd * mpx + (slot % mpx);
      ntile = slot / mpx;
    } else {
      mtile = blockIdx.y; ntile = blockIdx.x;
    }
  }
  const long tileM = (long)mtile * 256;
  const long tileN = (long)ntile * 256;

  const bf16* gA[2][2]; const bf16* gB[2][2];   // [mh|ks][j] base at k=0
  int lA[2][2], lB[2][2];
  {
    const int sc = l & 3;
#pragma unroll
    for (int j = 0; j < 2; ++j) {
      const int b = w * 2 + j;
      const int p = b >> 3, s = (b >> 2) & 1, blk = b & 3;
#pragma unroll
      for (int mh = 0; mh < 2; ++mh) {
        const int row = s * 128 + mh * 64 + blk * 16 + (l >> 2);
        const int cl = (sc - (row >> 1)) & 3;
        gA[mh][j] = A + (tileM + row) * (long)K + p * 32 + cl * 8;
        lA[mh][j] = p * 8192 + row * 32 + sc * 8;
      }
      const int rowB = b * 16 + (l >> 2);
      const int clB = (sc - (rowB >> 1)) & 3;
#pragma unroll
      for (int ks = 0; ks < 2; ++ks) {
        gB[ks][j] = B + (tileN + rowB) * (long)K + ks * 32 + clB * 8;
        lB[ks][j] = 16384 + ks * 8192 + rowB * 32 + sc * 8;
      }
    }
  }

  int offA[8], offB[4];
#pragma unroll
  for (int mh = 0; mh < 2; ++mh)
#pragma unroll
    for (int mi = 0; mi < 4; ++mi) {
      const int r = wr * 128 + mh * 64 + mi * 16 + m16;
      offA[mh * 4 + mi] = r * 32 + (((q + (r >> 1)) & 3) << 3);
    }
#pragma unroll
  for (int ni = 0; ni < 4; ++ni) {
    const int r = wcn * 64 + ni * 16 + m16;
    offB[ni] = r * 32 + (((q + (r >> 1)) & 3) << 3);
  }

  f32x4 acc[8][4] = {};

  int kb0A0 = 0, kb0B0 = 0, kb0B1 = 0, kb0A1 = 0;
  int kb1A0 = 64, kb1B0 = 64, kb1B1 = 64, kb1A1 = 64;

#define ST(BP, LO, BUF, KV)                                                    \
  { bf16* bb = ring + (BUF) * 32768;                                           \
    __builtin_amdgcn_global_load_lds(AS1((BP)[0] + (KV)), AS3(bb + (LO)[0]), 16, 0, 0); \
    __builtin_amdgcn_global_load_lds(AS1((BP)[1] + (KV)), AS3(bb + (LO)[1]), 16, 0, 0); \
    (KV) += 128; }

  // prologue: b0 {Am0, Bk0, Am1, Bk1}, b1 {Bk1, Am1}; WAIT6 -> P1+P2 set.
  ST(gA[0], lA[0], 0, kb0A0) ST(gB[0], lB[0], 0, kb0B0)
  ST(gA[1], lA[1], 0, kb0A1) ST(gB[1], lB[1], 0, kb0B1)
  ST(gB[1], lB[1], 1, kb1B1) ST(gA[1], lA[1], 1, kb1A1)
  WAIT6;
  __builtin_amdgcn_s_barrier();

  bf16x8 bv[4];
#define PHASE(BUF, MH, KS, LB, STG, WSTMT)                                     \
  {                                                                            \
    const bf16* pa = ring + (BUF) * 32768 + (KS) * 8192;                       \
    const bf16* pb = ring + (BUF) * 32768 + 16384 + (KS) * 8192;               \
    bf16x8 af[4];                                                              \
    _Pragma("unroll")                                                          \
    for (int mi = 0; mi < 4; ++mi)                                             \
      af[mi] = *(const bf16x8*)&pa[offA[(MH) * 4 + mi]];                       \
    if (LB) {                                                                  \
      _Pragma("unroll")                                                        \
      for (int ni = 0; ni < 4; ++ni)                                           \
        bv[ni] = *(const bf16x8*)&pb[offB[ni]];                                \
    }                                                                          \
    STG;                                                                       \
    WSTMT;                                                                     \
    __builtin_amdgcn_s_barrier();                                              \
    asm volatile("s_waitcnt lgkmcnt(0)");                                      \
    __builtin_amdgcn_s_setprio(1);                                             \
    _Pragma("unroll")                                                          \
    for (int mi = 0; mi < 4; ++mi) {                                           \
      _Pragma("unroll")                                                        \
      for (int ni = 0; ni < 4; ++ni)                                           \
        acc[(MH) * 4 + mi][ni] = __builtin_amdgcn_mfma_f32_16x16x32_bf16(      \
            af[mi], bv[ni], acc[(MH) * 4 + mi][ni], 0, 0, 0);                  \
    }                                                                          \
    __builtin_amdgcn_s_setprio(0);                                             \
    __builtin_amdgcn_s_barrier();                                              \
  }

  const int T = K >> 6;   // K-tiles; caller guarantees T even, T >= 4
#pragma unroll 1
  for (int i = 0; i < T / 2 - 1; ++i) {
    PHASE(0, 0, 0, 1, ST(gA[0], lA[0], 1, kb1A0), NOWAIT)   // P1
    PHASE(0, 1, 0, 0, ST(gB[0], lB[0], 1, kb1B0), WAIT8)    // P2
    PHASE(0, 1, 1, 1, ST(gB[0], lB[0], 0, kb0B0), NOWAIT)   // P3
    PHASE(0, 0, 1, 0, ST(gA[1], lA[1], 0, kb0A1), WAIT6)    // P4
    PHASE(1, 0, 1, 1, ST(gA[0], lA[0], 0, kb0A0), NOWAIT)   // P5
    PHASE(1, 1, 1, 0, ST(gB[1], lB[1], 0, kb0B1), WAIT8)    // P6
    PHASE(1, 1, 0, 1, ST(gB[1], lB[1], 1, kb1B1), NOWAIT)   // P7
    PHASE(1, 0, 0, 0, ST(gA[1], lA[1], 1, kb1A1), WAIT6)    // P8
  }
  // tail (tiles T-2, T-1): finish b1 staging at P1/P2, exact drain waits.
  PHASE(0, 0, 0, 1, ST(gA[0], lA[0], 1, kb1A0), NOWAIT)
  PHASE(0, 1, 0, 0, ST(gB[0], lB[0], 1, kb1B0), WAIT8)
  PHASE(0, 1, 1, 1, (void)0, NOWAIT)
  PHASE(0, 0, 1, 0, (void)0, WAIT2)
  PHASE(1, 0, 1, 1, (void)0, NOWAIT)
  PHASE(1, 1, 1, 0, (void)0, WAIT0)
  PHASE(1, 1, 0, 1, (void)0, NOWAIT)
  PHASE(1, 0, 0, 0, (void)0, NOWAIT)
#undef PHASE
#undef ST

  const long colBase = tileN + (long)wcn * 64 + m16;
  const long rowBase = tileM + (long)wr * 128 + q * 4;
#pragma unroll
  for (int mi = 0; mi < 8; ++mi) {
#pragma unroll
    for (int r = 0; r < 4; ++r) {
      const long row = rowBase + mi * 16 + r;
#pragma unroll
      for (int ni = 0; ni < 4; ++ni) {
        const long col = colBase + ni * 16;
        float v = acc[mi][ni][r];
        if (EPI == 0) {
          ((bf16*)out)[row * N + col] = (bf16)v;
        } else if (EPI == 1) {
          v += bias[col] + (float)resid[row * N + col];
          ((float*)out)[row * N + col] = v;
        } else if (EPI == 2) {
          v += bias[col];
          v = v > 0.f ? 1.0507009873554805f * v
                      : 1.0507009873554805f * 1.6732632423543772f * (__expf(v) - 1.f);
          ((bf16*)out)[row * N + col] = (bf16)v;
        } else {  // EPI == 3: bf16 = acc + bias + resid
          v += bias[col] + (float)resid[row * N + col];
          ((bf16*)out)[row * N + col] = (bf16)v;
        }
      }
    }
  }
}

// ---------------------------------------------------------------------------
extern "C" void kernel_launch(void* const* d_in, const int* in_sizes, int n_in,
                              void* d_out, int out_size, void* d_ws, size_t ws_size,
                              hipStream_t stream) {
  const float* patches   = (const float*)d_in[0];
  const float* in_weight = (const float*)d_in[1];
  const float* in_bias   = (const float*)d_in[2];
  const float* out_w     = (const float*)d_in[3];
  const float* out_b     = (const float*)d_in[4];
  const float* mlp_w1    = (const float*)d_in[5];
  const float* mlp_b1    = (const float*)d_in[6];
  const float* mlp_w2    = (const float*)d_in[7];
  const float* mlp_b2    = (const float*)d_in[8];
  const float* ln1_g     = (const float*)d_in[9];
  const float* ln1_b     = (const float*)d_in[10];
  const float* ln2_g     = (const float*)d_in[11];
  const float* ln2_b     = (const float*)d_in[12];

  char* ws = (char*)d_ws;
  const size_t MB = 1024 * 1024;
  bf16* Wc   = (bf16*)(ws + 0);        // [768][768] combined proj weight
  bf16* w1b  = (bf16*)(ws + 2 * MB);
  bf16* w2b  = (bf16*)(ws + 8 * MB);
  bf16* owb  = (bf16*)(ws + 14 * MB);
  bf16* wvt  = (bf16*)(ws + 16 * MB);
  float* bc  = (float*)(ws + 18 * MB);
  bf16* X1   = (bf16*)(ws + 20 * MB);  // 25 MB; reused as X3 after proj
  bf16* X3   = (bf16*)(ws + 20 * MB);
  bf16* X2b  = (bf16*)(ws + 48 * MB);  // 25 MB; dead before H written
  bf16* H    = (bf16*)(ws + 48 * MB);  // 100 MB (aliases X2b - safe, see order)

  prep_cast<<<(N1 + N2 + N3) / 256, 256, 0, stream>>>(mlp_w1, mlp_w2, out_w,
                                                      w1b, w2b, owb);
  wvt_kernel<<<dim3(12, 12), 256, 0, stream>>>(in_weight, wvt);
  bias_combine_kernel<<<768, 64, 0, stream>>>(out_w, in_bias, out_b, bc);
  // Wc[n][k] = sum_j out_w[n][j] * WvT[k][j]   (256^2 8-phase)
  gemm256<0><<<dim3(3, 3), 512, 0, stream>>>(owb, wvt, nullptr, nullptr, Wc, 768, 768, 768);

  ln_kernel<float><<<N_ROWS, 256, 0, stream>>>(patches, ln1_g, ln1_b, X1);
  // x2 = x1 @ Wc^T + bc + x1  (bf16)   (256^2 8-phase: N=768 small-N case)
  gemm256<3><<<dim3(3, 64), 512, 0, stream>>>(X1, Wc, bc, X1, X2b, N_ROWS, 768, 768);
  ln_kernel<bf16><<<N_ROWS, 256, 0, stream>>>(X2b, ln2_g, ln2_b, X3);
  // h = selu(x3 @ w1^T + b1)   (128^2 3-stage: best for MLPs)
  gemm128<2><<<dim3(24, 128), 256, 0, stream>>>(X3, w1b, mlp_b1, nullptr, H, N_ROWS, 3072, 768);
  // out = h @ w2^T + b2 + x3   (fp32 final)
  gemm128<1><<<dim3(6, 128), 256, 0, stream>>>(H, w2b, mlp_b2, X3, d_out, N_ROWS, 768, 3072);
}

// Round 8
// 387.863 us; speedup vs baseline: 2.3964x; 1.0639x over previous
//
#include <hip/hip_runtime.h>

// ============================================================================
// MixerBlock (attention QK^T/softmax is dead code; heads = V only):
//   x1 = LN1(patches); sa = x1 @ Wc^T + bc  (Wc = out_w @ Wv, precomputed)
//   x2 = sa + x1 (bf16, ws); x3 = LN2(x2)
//   h = selu(x3 @ w1^T + b1); out = h @ w2^T + b2 + x3
// R14 = assignment solved from R9/R11/R13 algebra (only gemm-variant
// assignment differed across those rounds):
//   R13-R11: (Wc+proj)_256 - (Wc+proj)_128 = +21.5 us -> proj/Wc faster at 128^2
//   R9-R13 : MLP2_256 - MLP2_128 = -35.1 us           -> MLP2 faster at 256^2
//   (MLP2 is the K=3072 GEMM: panel re-read traffic scales with K, so the
//   big tile pays off there; for K=768 the 256^2 schedule overhead wins.)
//   Assignment: Wc, proj, MLP1 -> gemm128 (R11 verbatim);
//               MLP2 -> gemm256 (R9 verbatim). No new kernel logic.
// Residency facts (R10-R12): LDS <= 64 KiB/block needed for co-residency;
// (256,3)+48 KiB is the VGPR-feasible optimum for 64x64 wave tiles;
// (256,5) spills acc (unified VGPR+AGPR budget ~102/wave -> 634 MB scratch).
// Kept: 16x16x32 MFMA, chunk swizzle (0 bank conflicts), global_load_lds
// w16, XCD m-band remap, bf16 X2 residency, merged casts, EPI fusion.
// ============================================================================

typedef __bf16 bf16;
typedef __bf16 bf16x8 __attribute__((ext_vector_type(8)));
typedef __bf16 bf16x4 __attribute__((ext_vector_type(4)));
typedef float  f32x4  __attribute__((ext_vector_type(4)));

#define N_ROWS  16384   // B*S = 8*2048

#define AS1(p) ((const __attribute__((address_space(1))) void*)(p))
#define AS3(p) ((__attribute__((address_space(3))) void*)(p))

// s_waitcnt imm (gfx9): vmcnt[3:0]|[15:14], expcnt[6:4]=7, lgkmcnt[11:8]=0xF
#define VM4 0x0F74
#define VM0 0x0F70
#define WAIT8  __builtin_amdgcn_s_waitcnt(0x0F78)
#define WAIT6  __builtin_amdgcn_s_waitcnt(0x0F76)
#define WAIT2  __builtin_amdgcn_s_waitcnt(0x0F72)
#define WAIT0  __builtin_amdgcn_s_waitcnt(0x0F70)
#define NOWAIT (void)0

// ---------------------------------------------------------------------------
// merged fp32->bf16 casts: mlp_w1 | mlp_w2 | out_w (4 elems/thread)
#define N1 589824   // 3072*768/4
#define N2 589824   // 768*3072/4
#define N3 147456   // 768*768/4
__global__ __launch_bounds__(256) void prep_cast(const float* __restrict__ w1,
                                                 const float* __restrict__ w2,
                                                 const float* __restrict__ ow,
                                                 bf16* __restrict__ w1b,
                                                 bf16* __restrict__ w2b,
                                                 bf16* __restrict__ owb) {
  int i = blockIdx.x * 256 + threadIdx.x;
  const float* src; bf16* dst; int off;
  if (i < N1)           { src = w1; dst = w1b; off = i; }
  else if (i < N1 + N2) { src = w2; dst = w2b; off = i - N1; }
  else                  { src = ow; dst = owb; off = i - N1 - N2; }
  float4 v = ((const float4*)src)[off];
  bf16x4 o = {(bf16)v.x, (bf16)v.y, (bf16)v.z, (bf16)v.w};
  *(bf16x4*)(dst + 4 * (size_t)off) = o;
}

// ---------------------------------------------------------------------------
// WvT[k][j] = in_weight[(j*3+2)*768 + k], LDS-tiled 64x64 (coalesced both ways)
__global__ __launch_bounds__(256) void wvt_kernel(const float* __restrict__ in_weight,
                                                  bf16* __restrict__ wvt) {
  __shared__ float t[64][65];
  const int k0 = blockIdx.x * 64, j0 = blockIdx.y * 64;
  const int tx = threadIdx.x & 63, ty = threadIdx.x >> 6;
  for (int jj = ty; jj < 64; jj += 4)
    t[jj][tx] = in_weight[((size_t)(j0 + jj) * 3 + 2) * 768 + k0 + tx];
  __syncthreads();
  for (int kk = ty; kk < 64; kk += 4)
    wvt[(size_t)(k0 + kk) * 768 + j0 + tx] = (bf16)t[tx][kk];
}

// ---------------------------------------------------------------------------
__global__ __launch_bounds__(64) void bias_combine_kernel(const float* __restrict__ out_w,
                                                          const float* __restrict__ in_bias,
                                                          const float* __restrict__ out_b,
                                                          float* __restrict__ bc) {
  int n = blockIdx.x, l = threadIdx.x;
  float s = 0.f;
  for (int j = l; j < 768; j += 64) s += out_w[(size_t)n * 768 + j] * in_bias[j * 3 + 2];
#pragma unroll
  for (int off = 32; off > 0; off >>= 1) s += __shfl_xor(s, off, 64);
  if (l == 0) bc[n] = s + out_b[n];
}

// ---------------------------------------------------------------------------
// LayerNorm: one row (768) per 256-thread block. TIN = float or bf16.
template <typename TIN>
__global__ __launch_bounds__(256) void ln_kernel(const TIN* __restrict__ x,
                                                 const float* __restrict__ g,
                                                 const float* __restrict__ b,
                                                 bf16* __restrict__ y) {
  const int row = blockIdx.x;
  const TIN* xr = x + (size_t)row * 768;
  float v[3], s1 = 0.f, s2 = 0.f;
#pragma unroll
  for (int i = 0; i < 3; ++i) {
    v[i] = (float)xr[threadIdx.x + i * 256];
    s1 += v[i];
    s2 += v[i] * v[i];
  }
#pragma unroll
  for (int off = 32; off > 0; off >>= 1) {
    s1 += __shfl_xor(s1, off, 64);
    s2 += __shfl_xor(s2, off, 64);
  }
  __shared__ float red[8];
  int w = threadIdx.x >> 6, l = threadIdx.x & 63;
  if (l == 0) { red[w * 2] = s1; red[w * 2 + 1] = s2; }
  __syncthreads();
  s1 = red[0] + red[2] + red[4] + red[6];
  s2 = red[1] + red[3] + red[5] + red[7];
  const float mu = s1 * (1.f / 768.f);
  const float var = s2 * (1.f / 768.f) - mu * mu;
  const float rstd = rsqrtf(var + 1e-5f);
#pragma unroll
  for (int i = 0; i < 3; ++i) {
    int d = threadIdx.x + i * 256;
    y[(size_t)row * 768 + d] = (bf16)((v[i] - mu) * rstd * g[d] + b[d]);
  }
}

// ---------------------------------------------------------------------------
// gemm128: C[M][N] = A[M][K] @ B[N][K]^T (+ epilogue). Block tile 128x128,
// BK=32, 256 threads = 4 waves 2x2 (wave tile 64x64, acc[4][4]). 3-stage LDS
// ring (48 KB -> up to 3 blocks/CU), prefetch distance 2, counted vmcnt.
// Requires K/32 % 3 == 0 (24, 96 ok); M,N % 128 == 0.  [R11 verbatim]
// EPI 0: bf16=acc | EPI 1: f32=acc+bias+resid | EPI 2: bf16=selu(acc+bias)
// EPI 3: bf16=acc+bias+resid
#define SLOT_E (256 * 32)   // (128 A-rows + 128 B-rows) * 32 k
template <int EPI>
__global__ __launch_bounds__(256, 3) void gemm128(const bf16* __restrict__ A,
                                                  const bf16* __restrict__ B,
                                                  const float* __restrict__ bias,
                                                  const bf16* __restrict__ resid,
                                                  void* __restrict__ out,
                                                  int M, int N, int K) {
  __shared__ bf16 ring[3 * SLOT_E];   // 48 KB
  const int tid = threadIdx.x;
  const int w = tid >> 6, l = tid & 63;
  const int wr = w >> 1, wcn = w & 1;       // 2x2 wave grid
  const int q = l >> 4, m16 = l & 15;

  // XCD-aware remap (XCD = linear%8): each XCD owns a contiguous band of
  // gridy/8 m-strips, m fastest -> A band L2-resident across n-tiles.
  int mtile, ntile;
  {
    const int L = blockIdx.y * gridDim.x + blockIdx.x;
    const int gy = gridDim.y;
    if ((gy & 7) == 0) {
      const int mpx = gy >> 3;
      const int xcd = L & 7;
      const int slot = L >> 3;
      mtile = xcd * mpx + (slot % mpx);
      ntile = slot / mpx;
    } else {
      mtile = blockIdx.y; ntile = blockIdx.x;
    }
  }
  const long tileM = (long)mtile * 128;
  const long tileN = (long)ntile * 128;

  // staging geometry (chunk swizzle: stored col (ch&3) holds logical col
  // ((ch&3)-(row>>1))&3 -> frag ds_read_b128 conflict-free).
  const bf16* gA[2]; int ldA[2];
  const bf16* gB[2]; int ldB[2];
#pragma unroll
  for (int j = 0; j < 2; ++j) {
    const int ch = tid + j * 256;
    const int row = ch >> 2;
    const int cl = ((ch & 3) - (row >> 1)) & 3;
    gA[j] = A + (tileM + row) * (long)K + cl * 8;
    gB[j] = B + (tileN + row) * (long)K + cl * 8;
    ldA[j] = ch * 8;
    ldB[j] = ch * 8;
  }

  // fragment LDS offsets (logical (r,q) lives at r*32 + ((q+(r>>1))&3)*8)
  int offA[4], offB[4];
#pragma unroll
  for (int mi = 0; mi < 4; ++mi) {
    const int r = wr * 64 + mi * 16 + m16;
    offA[mi] = r * 32 + (((q + (r >> 1)) & 3) << 3);
  }
#pragma unroll
  for (int ni = 0; ni < 4; ++ni) {
    const int r = wcn * 64 + ni * 16 + m16;
    offB[ni] = r * 32 + (((q + (r >> 1)) & 3) << 3);
  }

  f32x4 acc[4][4] = {};

  // prologue: stages 0..1 (4 loads/thread each: 2 A + 2 B)
#pragma unroll
  for (int s = 0; s < 2; ++s) {
    bf16* da = ring + s * SLOT_E;
    bf16* db = da + 128 * 32;
#pragma unroll
    for (int j = 0; j < 2; ++j) {
      __builtin_amdgcn_global_load_lds(AS1(gA[j] + s * 32), AS3(&da[ldA[j]]), 16, 0, 0);
      __builtin_amdgcn_global_load_lds(AS1(gB[j] + s * 32), AS3(&db[ldB[j]]), 16, 0, 0);
    }
  }
  long k_next = 64;

  // one K-step: wait(stage SLOT landed) -> barrier -> issue stage SLOT+2 ->
  // compute stage SLOT (16 MFMA, 8 ds_read_b128)
#define KSTEP(SLOT, WIMM, ISSUE)                                               \
  {                                                                            \
    __builtin_amdgcn_s_waitcnt(WIMM);                                          \
    __builtin_amdgcn_s_barrier();                                              \
    if (ISSUE) {                                                               \
      bf16* da = ring + (((SLOT) + 2) % 3) * SLOT_E;                           \
      bf16* db = da + 128 * 32;                                                \
      _Pragma("unroll")                                                        \
      for (int j = 0; j < 2; ++j) {                                            \
        __builtin_amdgcn_global_load_lds(AS1(gA[j] + k_next), AS3(&da[ldA[j]]), 16, 0, 0); \
        __builtin_amdgcn_global_load_lds(AS1(gB[j] + k_next), AS3(&db[ldB[j]]), 16, 0, 0); \
      }                                                                        \
      k_next += 32;                                                            \
    }                                                                          \
    const bf16* ca = ring + (SLOT) * SLOT_E;                                   \
    const bf16* cb = ca + 128 * 32;                                            \
    bf16x8 bfr[4];                                                             \
    _Pragma("unroll")                                                          \
    for (int ni = 0; ni < 4; ++ni) bfr[ni] = *(const bf16x8*)&cb[offB[ni]];    \
    _Pragma("unroll")                                                          \
    for (int mi = 0; mi < 4; ++mi) {                                           \
      const bf16x8 af = *(const bf16x8*)&ca[offA[mi]];                         \
      _Pragma("unroll")                                                        \
      for (int ni = 0; ni < 4; ++ni)                                           \
        acc[mi][ni] = __builtin_amdgcn_mfma_f32_16x16x32_bf16(af, bfr[ni],     \
                                                              acc[mi][ni], 0, 0, 0); \
    }                                                                          \
  }

  const int T = K >> 5;   // caller guarantees T % 3 == 0, T >= 6
#pragma unroll 1
  for (int g = 0; g < T - 3; g += 3) {
    KSTEP(0, VM4, 1) KSTEP(1, VM4, 1) KSTEP(2, VM4, 1)
  }
  KSTEP(0, VM4, 1) KSTEP(1, VM4, 0) KSTEP(2, VM0, 0)
#undef KSTEP

  // epilogue: C/D layout col = lane&15, row = (lane>>4)*4 + reg (m89-verified)
  const long colBase = tileN + (long)wcn * 64 + m16;
  const long rowBase = tileM + (long)wr * 64 + q * 4;
#pragma unroll
  for (int mi = 0; mi < 4; ++mi) {
#pragma unroll
    for (int r = 0; r < 4; ++r) {
      const long row = rowBase + mi * 16 + r;
#pragma unroll
      for (int ni = 0; ni < 4; ++ni) {
        const long col = colBase + ni * 16;
        float v = acc[mi][ni][r];
        if (EPI == 0) {
          ((bf16*)out)[row * N + col] = (bf16)v;
        } else if (EPI == 1) {
          v += bias[col] + (float)resid[row * N + col];
          ((float*)out)[row * N + col] = v;
        } else if (EPI == 2) {
          v += bias[col];
          v = v > 0.f ? 1.0507009873554805f * v
                      : 1.0507009873554805f * 1.6732632423543772f * (__expf(v) - 1.f);
          ((bf16*)out)[row * N + col] = (bf16)v;
        } else {  // EPI == 3: bf16 = acc + bias + resid
          v += bias[col] + (float)resid[row * N + col];
          ((bf16*)out)[row * N + col] = (bf16)v;
        }
      }
    }
  }
}

// ---------------------------------------------------------------------------
// gemm256: block tile 256x256, BK=64, 512 threads = 8 waves (2x4), wave tile
// 128x64, acc[8][4]. 8-phase schedule over 2 K-tiles (128 KiB LDS, 1 blk/CU).
// [R9 verbatim - used ONLY for MLP2 (K=3072): panel re-read traffic scales
// with K, so the big tile pays off there (-35 us measured); for K=768 GEMMs
// the 256^2 schedule overhead loses (+21.5 us on Wc+proj, +12.5 on MLP1).]
// Requires K % 128 == 0, K >= 256; M,N % 256 == 0.
template <int EPI>
__global__ __launch_bounds__(512, 2) void gemm256(const bf16* __restrict__ A,
                                                  const bf16* __restrict__ B,
                                                  const float* __restrict__ bias,
                                                  const bf16* __restrict__ resid,
                                                  void* __restrict__ out,
                                                  int M, int N, int K) {
  __shared__ bf16 ring[65536];   // 128 KiB = 2 bufs x (A 16384 + B 16384 elems)
  const int tid = threadIdx.x;
  const int w = tid >> 6, l = tid & 63;
  const int wr = w >> 2, wcn = w & 3;       // 2x4 wave grid
  const int q = l >> 4, m16 = l & 15;

  int mtile, ntile;
  {
    const int L = blockIdx.y * gridDim.x + blockIdx.x;
    const int gy = gridDim.y;
    if ((gy & 7) == 0) {
      const int mpx = gy >> 3;
      const int xcd = L & 7;
      const int slot = L >> 3;
      mtile = xcd * mpx + (slot % mpx);
      ntile = slot / mpx;
    } else {
      mtile = blockIdx.y; ntile = blockIdx.x;
    }
  }
  const long tileM = (long)mtile * 256;
  const long tileN = (long)ntile * 256;

  const bf16* gA[2][2]; const bf16* gB[2][2];   // [mh|ks][j] base at k=0
  int lA[2][2], lB[2][2];
  {
    const int sc = l & 3;
#pragma unroll
    for (int j = 0; j < 2; ++j) {
      const int b = w * 2 + j;
      const int p = b >> 3, s = (b >> 2) & 1, blk = b & 3;
#pragma unroll
      for (int mh = 0; mh < 2; ++mh) {
        const int row = s * 128 + mh * 64 + blk * 16 + (l >> 2);
        const int cl = (sc - (row >> 1)) & 3;
        gA[mh][j] = A + (tileM + row) * (long)K + p * 32 + cl * 8;
        lA[mh][j] = p * 8192 + row * 32 + sc * 8;
      }
      const int rowB = b * 16 + (l >> 2);
      const int clB = (sc - (rowB >> 1)) & 3;
#pragma unroll
      for (int ks = 0; ks < 2; ++ks) {
        gB[ks][j] = B + (tileN + rowB) * (long)K + ks * 32 + clB * 8;
        lB[ks][j] = 16384 + ks * 8192 + rowB * 32 + sc * 8;
      }
    }
  }

  int offA[8], offB[4];
#pragma unroll
  for (int mh = 0; mh < 2; ++mh)
#pragma unroll
    for (int mi = 0; mi < 4; ++mi) {
      const int r = wr * 128 + mh * 64 + mi * 16 + m16;
      offA[mh * 4 + mi] = r * 32 + (((q + (r >> 1)) & 3) << 3);
    }
#pragma unroll
  for (int ni = 0; ni < 4; ++ni) {
    const int r = wcn * 64 + ni * 16 + m16;
    offB[ni] = r * 32 + (((q + (r >> 1)) & 3) << 3);
  }

  f32x4 acc[8][4] = {};

  int kb0A0 = 0, kb0B0 = 0, kb0B1 = 0, kb0A1 = 0;
  int kb1A0 = 64, kb1B0 = 64, kb1B1 = 64, kb1A1 = 64;

#define ST(BP, LO, BUF, KV)                                                    \
  { bf16* bb = ring + (BUF) * 32768;                                           \
    __builtin_amdgcn_global_load_lds(AS1((BP)[0] + (KV)), AS3(bb + (LO)[0]), 16, 0, 0); \
    __builtin_amdgcn_global_load_lds(AS1((BP)[1] + (KV)), AS3(bb + (LO)[1]), 16, 0, 0); \
    (KV) += 128; }

  // prologue: b0 {Am0, Bk0, Am1, Bk1}, b1 {Bk1, Am1}; WAIT6 -> P1+P2 set.
  ST(gA[0], lA[0], 0, kb0A0) ST(gB[0], lB[0], 0, kb0B0)
  ST(gA[1], lA[1], 0, kb0A1) ST(gB[1], lB[1], 0, kb0B1)
  ST(gB[1], lB[1], 1, kb1B1) ST(gA[1], lA[1], 1, kb1A1)
  WAIT6;
  __builtin_amdgcn_s_barrier();

  bf16x8 bv[4];
#define PHASE(BUF, MH, KS, LB, STG, WSTMT)                                     \
  {                                                                            \
    const bf16* pa = ring + (BUF) * 32768 + (KS) * 8192;                       \
    const bf16* pb = ring + (BUF) * 32768 + 16384 + (KS) * 8192;               \
    bf16x8 af[4];                                                              \
    _Pragma("unroll")                                                          \
    for (int mi = 0; mi < 4; ++mi)                                             \
      af[mi] = *(const bf16x8*)&pa[offA[(MH) * 4 + mi]];                       \
    if (LB) {                                                                  \
      _Pragma("unroll")                                                        \
      for (int ni = 0; ni < 4; ++ni)                                           \
        bv[ni] = *(const bf16x8*)&pb[offB[ni]];                                \
    }                                                                          \
    STG;                                                                       \
    WSTMT;                                                                     \
    __builtin_amdgcn_s_barrier();                                              \
    asm volatile("s_waitcnt lgkmcnt(0)");                                      \
    __builtin_amdgcn_s_setprio(1);                                             \
    _Pragma("unroll")                                                          \
    for (int mi = 0; mi < 4; ++mi) {                                           \
      _Pragma("unroll")                                                        \
      for (int ni = 0; ni < 4; ++ni)                                           \
        acc[(MH) * 4 + mi][ni] = __builtin_amdgcn_mfma_f32_16x16x32_bf16(      \
            af[mi], bv[ni], acc[(MH) * 4 + mi][ni], 0, 0, 0);                  \
    }                                                                          \
    __builtin_amdgcn_s_setprio(0);                                             \
    __builtin_amdgcn_s_barrier();                                              \
  }

  const int T = K >> 6;   // K-tiles; caller guarantees T even, T >= 4
#pragma unroll 1
  for (int i = 0; i < T / 2 - 1; ++i) {
    PHASE(0, 0, 0, 1, ST(gA[0], lA[0], 1, kb1A0), NOWAIT)   // P1
    PHASE(0, 1, 0, 0, ST(gB[0], lB[0], 1, kb1B0), WAIT8)    // P2
    PHASE(0, 1, 1, 1, ST(gB[0], lB[0], 0, kb0B0), NOWAIT)   // P3
    PHASE(0, 0, 1, 0, ST(gA[1], lA[1], 0, kb0A1), WAIT6)    // P4
    PHASE(1, 0, 1, 1, ST(gA[0], lA[0], 0, kb0A0), NOWAIT)   // P5
    PHASE(1, 1, 1, 0, ST(gB[1], lB[1], 0, kb0B1), WAIT8)    // P6
    PHASE(1, 1, 0, 1, ST(gB[1], lB[1], 1, kb1B1), NOWAIT)   // P7
    PHASE(1, 0, 0, 0, ST(gA[1], lA[1], 1, kb1A1), WAIT6)    // P8
  }
  // tail (tiles T-2, T-1): finish b1 staging at P1/P2, exact drain waits.
  PHASE(0, 0, 0, 1, ST(gA[0], lA[0], 1, kb1A0), NOWAIT)
  PHASE(0, 1, 0, 0, ST(gB[0], lB[0], 1, kb1B0), WAIT8)
  PHASE(0, 1, 1, 1, (void)0, NOWAIT)
  PHASE(0, 0, 1, 0, (void)0, WAIT2)
  PHASE(1, 0, 1, 1, (void)0, NOWAIT)
  PHASE(1, 1, 1, 0, (void)0, WAIT0)
  PHASE(1, 1, 0, 1, (void)0, NOWAIT)
  PHASE(1, 0, 0, 0, (void)0, NOWAIT)
#undef PHASE
#undef ST

  const long colBase = tileN + (long)wcn * 64 + m16;
  const long rowBase = tileM + (long)wr * 128 + q * 4;
#pragma unroll
  for (int mi = 0; mi < 8; ++mi) {
#pragma unroll
    for (int r = 0; r < 4; ++r) {
      const long row = rowBase + mi * 16 + r;
#pragma unroll
      for (int ni = 0; ni < 4; ++ni) {
        const long col = colBase + ni * 16;
        float v = acc[mi][ni][r];
        if (EPI == 0) {
          ((bf16*)out)[row * N + col] = (bf16)v;
        } else if (EPI == 1) {
          v += bias[col] + (float)resid[row * N + col];
          ((float*)out)[row * N + col] = v;
        } else if (EPI == 2) {
          v += bias[col];
          v = v > 0.f ? 1.0507009873554805f * v
                      : 1.0507009873554805f * 1.6732632423543772f * (__expf(v) - 1.f);
          ((bf16*)out)[row * N + col] = (bf16)v;
        } else {  // EPI == 3: bf16 = acc + bias + resid
          v += bias[col] + (float)resid[row * N + col];
          ((bf16*)out)[row * N + col] = (bf16)v;
        }
      }
    }
  }
}

// ---------------------------------------------------------------------------
extern "C" void kernel_launch(void* const* d_in, const int* in_sizes, int n_in,
                              void* d_out, int out_size, void* d_ws, size_t ws_size,
                              hipStream_t stream) {
  const float* patches   = (const float*)d_in[0];
  const float* in_weight = (const float*)d_in[1];
  const float* in_bias   = (const float*)d_in[2];
  const float* out_w     = (const float*)d_in[3];
  const float* out_b     = (const float*)d_in[4];
  const float* mlp_w1    = (const float*)d_in[5];
  const float* mlp_b1    = (const float*)d_in[6];
  const float* mlp_w2    = (const float*)d_in[7];
  const float* mlp_b2    = (const float*)d_in[8];
  const float* ln1_g     = (const float*)d_in[9];
  const float* ln1_b     = (const float*)d_in[10];
  const float* ln2_g     = (const float*)d_in[11];
  const float* ln2_b     = (const float*)d_in[12];

  char* ws = (char*)d_ws;
  const size_t MB = 1024 * 1024;
  bf16* Wc   = (bf16*)(ws + 0);        // [768][768] combined proj weight
  bf16* w1b  = (bf16*)(ws + 2 * MB);
  bf16* w2b  = (bf16*)(ws + 8 * MB);
  bf16* owb  = (bf16*)(ws + 14 * MB);
  bf16* wvt  = (bf16*)(ws + 16 * MB);
  float* bc  = (float*)(ws + 18 * MB);
  bf16* X1   = (bf16*)(ws + 20 * MB);  // 25 MB; reused as X3 after proj
  bf16* X3   = (bf16*)(ws + 20 * MB);
  bf16* X2b  = (bf16*)(ws + 48 * MB);  // 25 MB; dead before H written
  bf16* H    = (bf16*)(ws + 48 * MB);  // 100 MB (aliases X2b - safe, see order)

  prep_cast<<<(N1 + N2 + N3) / 256, 256, 0, stream>>>(mlp_w1, mlp_w2, out_w,
                                                      w1b, w2b, owb);
  wvt_kernel<<<dim3(12, 12), 256, 0, stream>>>(in_weight, wvt);
  bias_combine_kernel<<<768, 64, 0, stream>>>(out_w, in_bias, out_b, bc);
  // Wc[n][k] = sum_j out_w[n][j] * WvT[k][j]   (128^2: K=768 case)
  gemm128<0><<<dim3(6, 6), 256, 0, stream>>>(owb, wvt, nullptr, nullptr, Wc, 768, 768, 768);

  ln_kernel<float><<<N_ROWS, 256, 0, stream>>>(patches, ln1_g, ln1_b, X1);
  // x2 = x1 @ Wc^T + bc + x1  (bf16)   (128^2: K=768)
  gemm128<3><<<dim3(6, 128), 256, 0, stream>>>(X1, Wc, bc, X1, X2b, N_ROWS, 768, 768);
  ln_kernel<bf16><<<N_ROWS, 256, 0, stream>>>(X2b, ln2_g, ln2_b, X3);
  // h = selu(x3 @ w1^T + b1)   (128^2: K=768)
  gemm128<2><<<dim3(24, 128), 256, 0, stream>>>(X3, w1b, mlp_b1, nullptr, H, N_ROWS, 3072, 768);
  // out = h @ w2^T + b2 + x3   (fp32 final)   (256^2 8-phase: K=3072)
  gemm256<1><<<dim3(3, 64), 512, 0, stream>>>(H, w2b, mlp_b2, X3, d_out, N_ROWS, 768, 3072);
}